// Round 1
// 983.032 us; speedup vs baseline: 1.0150x; 1.0150x over previous
//
#include <hip/hip_runtime.h>
#include <hip/hip_bf16.h>
#include <hip/hip_fp16.h>

// Problem dims (fixed)
#define S_LEN  4096
#define BATCH  8
#define HD     1024          // D == H
#define N3     3072          // 3H
#define MTOT   (S_LEN * BATCH)   // 32768 GEMM rows
#define KD     1024          // GEMM K
#define CHUNK  64
#define NCHUNK (S_LEN / CHUNK)   // 64

typedef __bf16 bf16x8 __attribute__((ext_vector_type(8)));
typedef float  f32x4  __attribute__((ext_vector_type(4)));

__device__ __forceinline__ float sigmoid_f(float x) {
    return 1.0f / (1.0f + __expf(-x));
}
__device__ __forceinline__ float tanh_f(float x) {
    return 1.0f - 2.0f / (__expf(2.0f * x) + 1.0f);
}

// ---------------------------------------------------------------------------
// fp32 -> bf16 elementwise convert (8 elems/thread, exact grid)
// ---------------------------------------------------------------------------
__global__ __launch_bounds__(256)
void cvt_f32_to_bf16(const float* __restrict__ in, __hip_bfloat16* __restrict__ out)
{
    const size_t i = ((size_t)blockIdx.x * 256 + threadIdx.x) * 8;
    const float4 a = *(const float4*)(in + i);
    const float4 b = *(const float4*)(in + i + 4);
    bf16x8 v;
    v[0] = (__bf16)a.x; v[1] = (__bf16)a.y; v[2] = (__bf16)a.z; v[3] = (__bf16)a.w;
    v[4] = (__bf16)b.x; v[5] = (__bf16)b.y; v[6] = (__bf16)b.z; v[7] = (__bf16)b.w;
    *(bf16x8*)((__bf16*)out + i) = v;
}

// ---------------------------------------------------------------------------
// W [K,N] fp32 -> Wt [N,K] bf16, 32x32 LDS tiles
// ---------------------------------------------------------------------------
__global__ __launch_bounds__(256)
void transpose_w(const float* __restrict__ W, __hip_bfloat16* __restrict__ Wt)
{
    __shared__ float tile[32][33];
    const int n0 = blockIdx.x * 32;
    const int k0 = blockIdx.y * 32;
    const int tx = threadIdx.x;      // 0..31
    const int ty = threadIdx.y;      // 0..7
    #pragma unroll
    for (int r = ty; r < 32; r += 8)
        tile[r][tx] = W[(size_t)(k0 + r) * N3 + n0 + tx];
    __syncthreads();
    #pragma unroll
    for (int r = ty; r < 32; r += 8)
        Wt[(size_t)(n0 + r) * KD + k0 + tx] = __float2bfloat16(tile[tx][r]);
}

// ---------------------------------------------------------------------------
// GEMM: G[m,n] = act( A[m,:] . Bt[n,:] + bias[n] ),  act = sigmoid for n>=H
// 256x256 tile, BK=64, 8 waves of 128x64, mfma_f32_16x16x32_bf16.
// 8-phase-style schedule: 4 phases/K-tile, global_load_lds direct staging
// into just-consumed regions of the same buffer (prefetch distance = 2
// K-tiles), counted vmcnt(8) once per K-tile, raw s_barrier + pinned
// lgkmcnt(0), XOR LDS swizzle (colE ^= (row&7)<<3) both-sides, setprio
// around MFMA clusters, bijective XCD blockIdx swizzle.
// ---------------------------------------------------------------------------
#define TILE_E (256 * 64)    // elements in one 256x64 bf16 LDS tile

__device__ __forceinline__ void gload16(const __hip_bfloat16* g, __hip_bfloat16* l)
{
    __builtin_amdgcn_global_load_lds(
        (const __attribute__((address_space(1))) void*)g,
        (__attribute__((address_space(3))) void*)l,
        16, 0, 0);
}

__global__ __launch_bounds__(512, 2)
void gemm_gates(const __hip_bfloat16* __restrict__ A,
                const __hip_bfloat16* __restrict__ Bt,
                const float* __restrict__ bias,
                __half* __restrict__ G)
{
    __shared__ __hip_bfloat16 sA[2 * TILE_E];   // 64 KiB
    __shared__ __hip_bfloat16 sB[2 * TILE_E];   // 64 KiB

    const int tid  = threadIdx.x;
    const int wave = tid >> 6;
    const int lane = tid & 63;
    const int l15  = lane & 15;
    const int quad = lane >> 4;

    // bijective XCD swizzle (nwg = 1536, 1536 % 8 == 0)
    int id = (int)blockIdx.x;
    id = (id & 7) * (1536 / 8) + (id >> 3);
    const int mt = id / (N3 / 256);
    const int nt = id % (N3 / 256);
    const int m0 = mt * 256;
    const int n0 = nt * 256;

    const int wm = (wave >> 2) * 128;   // 0 or 128
    const int wn = (wave & 3) * 64;     // 0,64,128,192

    // swizzled fragment column offsets (elements): col = kk*32 + quad*8
    const int swz = (l15 & 7) << 3;
    const int ce0 = (quad * 8) ^ swz;          // kk = 0
    const int ce1 = ce0 ^ 32;                  // kk = 1

    // staging geometry: each region = 64 rows x 64 cols = 512 thr x 16 B
    const int srr  = lane >> 3;                       // row within wave's strip
    const int sce  = ((lane & 7) * 8) ^ (srr << 3);   // pre-swizzled global col
    const int a_gr = m0 + wave * 8 + srr;             // + q*64
    const int b_gr = n0 + wave * 8 + srr;             // + q*64
    const int sloff = wave * 8 * 64;                  // wave-uniform LDS offset

    f32x4 acc[8][4] = {};

    // ---- prologue: stage K-tile 0 -> buf0, K-tile 1 -> buf1 ----
    #pragma unroll
    for (int q = 0; q < 4; ++q)
        gload16(A  + (size_t)(a_gr + q * 64) * KD + 0  + sce, sA + sloff + q * 4096);
    #pragma unroll
    for (int q = 0; q < 4; ++q)
        gload16(Bt + (size_t)(b_gr + q * 64) * KD + 0  + sce, sB + sloff + q * 4096);
    #pragma unroll
    for (int q = 0; q < 4; ++q)
        gload16(A  + (size_t)(a_gr + q * 64) * KD + 64 + sce, sA + TILE_E + sloff + q * 4096);
    #pragma unroll
    for (int q = 0; q < 4; ++q)
        gload16(Bt + (size_t)(b_gr + q * 64) * KD + 64 + sce, sB + TILE_E + sloff + q * 4096);

    asm volatile("s_waitcnt vmcnt(8)" ::: "memory");
    asm volatile("s_barrier" ::: "memory");

    #pragma unroll 1
    for (int t = 0; t < 16; ++t) {
        __hip_bfloat16* pA = sA + (t & 1) * TILE_E;
        __hip_bfloat16* pB = sB + (t & 1) * TILE_E;
        const int ktn = t * 64 + 128;          // K-offset of K-tile t+2
        const bool st = (t < 14);

        bf16x8 af[4][2], b01[2][2], b23[2][2];

        // ================= phase 1: a(i0-3), b(t0-1) -> acc[0..3][0..1]
        #pragma unroll
        for (int i = 0; i < 4; ++i) {
            const int ro = (wm + i * 16 + l15) * 64;
            af[i][0] = *(const bf16x8*)(pA + ro + ce0);
            af[i][1] = *(const bf16x8*)(pA + ro + ce1);
        }
        #pragma unroll
        for (int j = 0; j < 2; ++j) {
            const int ro = (wn + j * 16 + l15) * 64;
            b01[j][0] = *(const bf16x8*)(pB + ro + ce0);
            b01[j][1] = *(const bf16x8*)(pB + ro + ce1);
        }
        asm volatile("s_barrier" ::: "memory");
        asm volatile("s_waitcnt lgkmcnt(0)" ::: "memory");
        __builtin_amdgcn_s_setprio(1);
        #pragma unroll
        for (int i = 0; i < 4; ++i)
            #pragma unroll
            for (int j = 0; j < 2; ++j) {
                acc[i][j] = __builtin_amdgcn_mfma_f32_16x16x32_bf16(af[i][0], b01[j][0], acc[i][j], 0, 0, 0);
                acc[i][j] = __builtin_amdgcn_mfma_f32_16x16x32_bf16(af[i][1], b01[j][1], acc[i][j], 0, 0, 0);
            }
        __builtin_amdgcn_s_setprio(0);
        asm volatile("s_barrier" ::: "memory");

        // ================= phase 2: b(t2-3) -> acc[0..3][2..3]; stage A q0,q2
        #pragma unroll
        for (int j = 0; j < 2; ++j) {
            const int ro = (wn + (2 + j) * 16 + l15) * 64;
            b23[j][0] = *(const bf16x8*)(pB + ro + ce0);
            b23[j][1] = *(const bf16x8*)(pB + ro + ce1);
        }
        if (st) {  // A q0 (rows 0-63) and q2 (128-191): consumed in phase 1
            gload16(A + (size_t)(a_gr + 0 * 64) * KD + ktn + sce, pA + sloff + 0 * 4096);
            gload16(A + (size_t)(a_gr + 2 * 64) * KD + ktn + sce, pA + sloff + 2 * 4096);
        }
        asm volatile("s_barrier" ::: "memory");
        asm volatile("s_waitcnt lgkmcnt(0)" ::: "memory");
        __builtin_amdgcn_s_setprio(1);
        #pragma unroll
        for (int i = 0; i < 4; ++i)
            #pragma unroll
            for (int j = 0; j < 2; ++j) {
                acc[i][2 + j] = __builtin_amdgcn_mfma_f32_16x16x32_bf16(af[i][0], b23[j][0], acc[i][2 + j], 0, 0, 0);
                acc[i][2 + j] = __builtin_amdgcn_mfma_f32_16x16x32_bf16(af[i][1], b23[j][1], acc[i][2 + j], 0, 0, 0);
            }
        __builtin_amdgcn_s_setprio(0);
        asm volatile("s_barrier" ::: "memory");

        // ================= phase 3: a(i4-7) -> acc[4..7][2..3]; stage B q0-q2
        #pragma unroll
        for (int i = 0; i < 4; ++i) {
            const int ro = (wm + 64 + i * 16 + l15) * 64;
            af[i][0] = *(const bf16x8*)(pA + ro + ce0);
            af[i][1] = *(const bf16x8*)(pA + ro + ce1);
        }
        if (st) {  // all of B consumed by end of phase 2
            gload16(Bt + (size_t)(b_gr + 0 * 64) * KD + ktn + sce, pB + sloff + 0 * 4096);
            gload16(Bt + (size_t)(b_gr + 1 * 64) * KD + ktn + sce, pB + sloff + 1 * 4096);
            gload16(Bt + (size_t)(b_gr + 2 * 64) * KD + ktn + sce, pB + sloff + 2 * 4096);
        }
        asm volatile("s_barrier" ::: "memory");
        asm volatile("s_waitcnt lgkmcnt(0)" ::: "memory");
        __builtin_amdgcn_s_setprio(1);
        #pragma unroll
        for (int i = 0; i < 4; ++i)
            #pragma unroll
            for (int j = 0; j < 2; ++j) {
                acc[4 + i][2 + j] = __builtin_amdgcn_mfma_f32_16x16x32_bf16(af[i][0], b23[j][0], acc[4 + i][2 + j], 0, 0, 0);
                acc[4 + i][2 + j] = __builtin_amdgcn_mfma_f32_16x16x32_bf16(af[i][1], b23[j][1], acc[4 + i][2 + j], 0, 0, 0);
            }
        __builtin_amdgcn_s_setprio(0);
        asm volatile("s_barrier" ::: "memory");

        // ================= phase 4: regs only -> acc[4..7][0..1]; stage B q3, A q1,q3
        if (st) {  // B q3 consumed ph2; A q1 (64-127), q3 (192-255) consumed ph3
            gload16(Bt + (size_t)(b_gr + 3 * 64) * KD + ktn + sce, pB + sloff + 3 * 4096);
            gload16(A  + (size_t)(a_gr + 1 * 64) * KD + ktn + sce, pA + sloff + 1 * 4096);
            gload16(A  + (size_t)(a_gr + 3 * 64) * KD + ktn + sce, pA + sloff + 3 * 4096);
        }
        asm volatile("s_barrier" ::: "memory");
        __builtin_amdgcn_s_setprio(1);
        #pragma unroll
        for (int i = 0; i < 4; ++i)
            #pragma unroll
            for (int j = 0; j < 2; ++j) {
                acc[4 + i][j] = __builtin_amdgcn_mfma_f32_16x16x32_bf16(af[i][0], b01[j][0], acc[4 + i][j], 0, 0, 0);
                acc[4 + i][j] = __builtin_amdgcn_mfma_f32_16x16x32_bf16(af[i][1], b01[j][1], acc[4 + i][j], 0, 0, 0);
            }
        __builtin_amdgcn_s_setprio(0);
        // counted drain: leave this K-tile's 8 stage loads in flight,
        // guarantee K-tile t+1's loads have landed (then barrier joins waves)
        if (st) asm volatile("s_waitcnt vmcnt(8)" ::: "memory");
        else    asm volatile("s_waitcnt vmcnt(0)" ::: "memory");
        asm volatile("s_barrier" ::: "memory");
    }

    // ---- epilogue: bias + sigmoid(n>=H), fp16 store ----
    // D layout: row = quad*4 + r, col = l15
    #pragma unroll
    for (int tt = 0; tt < 4; ++tt) {
        const int n = n0 + wn + tt * 16 + l15;
        const float bv = bias[n];
        const bool sig = (n >= HD);
        #pragma unroll
        for (int i = 0; i < 8; ++i) {
            #pragma unroll
            for (int r = 0; r < 4; ++r) {
                const int m = m0 + wm + i * 16 + quad * 4 + r;
                float v = acc[i][tt][r] + bv;
                if (sig) v = sigmoid_f(v);
                G[(size_t)m * N3 + n] = __float2half(v);
            }
        }
    }
}

// ---------------------------------------------------------------------------
// Scan pass A: per-chunk affine composition. c_out = Aacc * c_in + Bacc
// ---------------------------------------------------------------------------
__global__ __launch_bounds__(256)
void scan_a(const __half* __restrict__ G,
            float* __restrict__ cA, float* __restrict__ cB)
{
    const int tid = threadIdx.x;
    const int h = (blockIdx.x & 3) * 256 + tid;
    const int b = (blockIdx.x >> 2) & 7;
    const int j = blockIdx.x >> 5;

    const size_t step = (size_t)BATCH * N3;
    const size_t base = ((size_t)(j * CHUNK) * BATCH + b) * N3;
    const __half* pu = G + base + h;
    const __half* pf = G + base + HD + h;

    float Aacc = 1.0f, Bacc = 0.0f;
    #pragma unroll 4
    for (int s = 0; s < CHUNK; ++s) {
        const float f = __half2float(*pf);
        const float u = __half2float(*pu);
        Bacc = f * Bacc + (1.0f - f) * u;
        Aacc *= f;
        pu += step; pf += step;
    }
    const int idx = (j * BATCH + b) * HD + h;
    cA[idx] = Aacc;
    cB[idx] = Bacc;
}

// ---------------------------------------------------------------------------
// Scan pass B: sequential prefix over chunks; emits chunk-start c and c_last
// ---------------------------------------------------------------------------
__global__ __launch_bounds__(256)
void scan_b(const float* __restrict__ cA, const float* __restrict__ cB,
            const float* __restrict__ h0,        // [B*H] slice for this layer
            float* __restrict__ cstart,          // [NCHUNK,B,H]
            float* __restrict__ c_out)           // [B*H] hidden slot (fp32)
{
    const int tid = blockIdx.x * 256 + threadIdx.x;  // 0..8191
    const int b = tid >> 10;
    const int h = tid & 1023;
    float c = h0[b * HD + h];
    #pragma unroll 8
    for (int j = 0; j < NCHUNK; ++j) {
        const int idx = (j * BATCH + b) * HD + h;
        cstart[idx] = c;
        c = cA[idx] * c + cB[idx];
    }
    c_out[b * HD + h] = c;
}

// ---------------------------------------------------------------------------
// Scan pass C: replay chunk; h = o*tanh(c) + (1-o)*x
// OUT_F32=false: write bf16 (layer-1 h1, may alias xin — read precedes write)
// OUT_F32=true : write fp32 (layer-2 final output)
// ---------------------------------------------------------------------------
template<bool OUT_F32>
__global__ __launch_bounds__(256)
void scan_c(const __half* __restrict__ G,
            const __hip_bfloat16* __restrict__ xin,
            const float* __restrict__ cstart,
            __hip_bfloat16* __restrict__ hout_bf,
            float* __restrict__ hout_f32)
{
    const int tid = threadIdx.x;
    const int h = (blockIdx.x & 3) * 256 + tid;
    const int b = (blockIdx.x >> 2) & 7;
    const int j = blockIdx.x >> 5;

    float c = cstart[(j * BATCH + b) * HD + h];

    const size_t mbase = (size_t)(j * CHUNK) * BATCH + b;
    const size_t stepg = (size_t)BATCH * N3;
    const size_t steph = (size_t)BATCH * HD;
    const __half* pu = G + mbase * N3 + h;
    const __half* pf = pu + HD;
    const __half* po = pu + 2 * HD;
    const __hip_bfloat16* px = xin + mbase * HD + h;
    __hip_bfloat16* pb = hout_bf ? hout_bf + mbase * HD + h : nullptr;
    float* pw = hout_f32 ? hout_f32 + mbase * HD + h : nullptr;

    #pragma unroll 4
    for (int s = 0; s < CHUNK; ++s) {
        const float f = __half2float(*pf);
        const float u = __half2float(*pu);
        const float o = __half2float(*po);
        const float x = __bfloat162float(*px);
        c = f * c + (1.0f - f) * u;
        const float hv = o * tanh_f(c) + (1.0f - o) * x;
        if (OUT_F32) { *pw = hv; pw += steph; }
        else         { *pb = __float2bfloat16(hv); pb += steph; }
        pu += stepg; pf += stepg; po += stepg; px += steph;
    }
}

// ---------------------------------------------------------------------------
extern "C" void kernel_launch(void* const* d_in, const int* in_sizes, int n_in,
                              void* d_out, int out_size, void* d_ws, size_t ws_size,
                              hipStream_t stream)
{
    const float* x  = (const float*)d_in[0];
    const float* h0 = (const float*)d_in[1];
    const float* W1 = (const float*)d_in[2];
    const float* b1 = (const float*)d_in[3];
    const float* W2 = (const float*)d_in[4];
    const float* b2 = (const float*)d_in[5];

    float* out     = (float*)d_out;
    float* h2_out  = out;                                  // [S,B,H] fp32
    float* hid_out = out + (size_t)S_LEN * BATCH * HD;     // [2,B,H] fp32

    // workspace carve-up (~268 MiB)
    char* ws = (char*)d_ws;
    auto carve = [&ws](size_t bytes) {
        char* p = ws;
        ws += (bytes + 255) & ~(size_t)255;
        return p;
    };
    const size_t G_BYTES   = (size_t)MTOT * N3 * 2;            // 192 MiB (fp16)
    const size_t XB_BYTES  = (size_t)MTOT * HD * 2;            // 64 MiB (bf16)
    const size_t WT_BYTES  = (size_t)N3 * KD * 2;              // 6 MiB (bf16)
    const size_t CAB_BYTES = (size_t)NCHUNK * BATCH * HD * 4;  // 2 MiB each

    __half* G           = (__half*)carve(G_BYTES);
    __hip_bfloat16* xb  = (__hip_bfloat16*)carve(XB_BYTES);  // x bf16; reused as h1
    __hip_bfloat16* Wt  = (__hip_bfloat16*)carve(WT_BYTES);
    float* cA           = (float*)carve(CAB_BYTES);
    float* cB           = (float*)carve(CAB_BYTES);
    float* cstart       = (float*)carve(CAB_BYTES);

    const dim3 tpb_t(32, 8);
    const dim3 grid_t(N3 / 32, KD / 32);
    const int  grid_gemm = (MTOT / 256) * (N3 / 256);   // 1536
    const int scan_blocks = NCHUNK * BATCH * 4;   // 2048
    const int cvt_blocks  = (int)(((size_t)MTOT * HD) / (256 * 8));  // 16384

    // ---- layer 1 ----
    cvt_f32_to_bf16<<<cvt_blocks, 256, 0, stream>>>(x, xb);
    transpose_w<<<grid_t, tpb_t, 0, stream>>>(W1, Wt);
    gemm_gates<<<grid_gemm, 512, 0, stream>>>(xb, Wt, b1, G);
    scan_a<<<scan_blocks, 256, 0, stream>>>(G, cA, cB);
    scan_b<<<32, 256, 0, stream>>>(cA, cB, h0, cstart, hid_out);
    // writes h1 over xb in place (per-element read precedes write)
    scan_c<false><<<scan_blocks, 256, 0, stream>>>(G, xb, cstart, xb, nullptr);

    // ---- layer 2 ----
    transpose_w<<<grid_t, tpb_t, 0, stream>>>(W2, Wt);
    gemm_gates<<<grid_gemm, 512, 0, stream>>>(xb, Wt, b2, G);
    scan_a<<<scan_blocks, 256, 0, stream>>>(G, cA, cB);
    scan_b<<<32, 256, 0, stream>>>(cA, cB, h0 + (size_t)BATCH * HD, cstart,
                                   hid_out + (size_t)BATCH * HD);
    scan_c<true><<<scan_blocks, 256, 0, stream>>>(G, xb, cstart, nullptr, h2_out);
}

// Round 2
// 981.760 us; speedup vs baseline: 1.0163x; 1.0013x over previous
//
#include <hip/hip_runtime.h>
#include <hip/hip_bf16.h>
#include <hip/hip_fp16.h>

// Problem dims (fixed)
#define S_LEN  4096
#define BATCH  8
#define HD     1024          // D == H
#define N3     3072          // 3H
#define MTOT   (S_LEN * BATCH)   // 32768 GEMM rows
#define KD     1024          // GEMM K
#define CHUNK  64
#define NCHUNK (S_LEN / CHUNK)   // 64

typedef __bf16 bf16x8 __attribute__((ext_vector_type(8)));
typedef float  f32x4  __attribute__((ext_vector_type(4)));

__device__ __forceinline__ float sigmoid_f(float x) {
    return 1.0f / (1.0f + __expf(-x));
}
__device__ __forceinline__ float tanh_f(float x) {
    return 1.0f - 2.0f / (__expf(2.0f * x) + 1.0f);
}

// ---------------------------------------------------------------------------
// fp32 -> bf16 elementwise convert (8 elems/thread, exact grid)
// ---------------------------------------------------------------------------
__global__ __launch_bounds__(256)
void cvt_f32_to_bf16(const float* __restrict__ in, __hip_bfloat16* __restrict__ out)
{
    const size_t i = ((size_t)blockIdx.x * 256 + threadIdx.x) * 8;
    const float4 a = *(const float4*)(in + i);
    const float4 b = *(const float4*)(in + i + 4);
    bf16x8 v;
    v[0] = (__bf16)a.x; v[1] = (__bf16)a.y; v[2] = (__bf16)a.z; v[3] = (__bf16)a.w;
    v[4] = (__bf16)b.x; v[5] = (__bf16)b.y; v[6] = (__bf16)b.z; v[7] = (__bf16)b.w;
    *(bf16x8*)((__bf16*)out + i) = v;
}

// ---------------------------------------------------------------------------
// W [K,N] fp32 -> Wt [N,K] bf16, 32x32 LDS tiles
// ---------------------------------------------------------------------------
__global__ __launch_bounds__(256)
void transpose_w(const float* __restrict__ W, __hip_bfloat16* __restrict__ Wt)
{
    __shared__ float tile[32][33];
    const int n0 = blockIdx.x * 32;
    const int k0 = blockIdx.y * 32;
    const int tx = threadIdx.x;      // 0..31
    const int ty = threadIdx.y;      // 0..7
    #pragma unroll
    for (int r = ty; r < 32; r += 8)
        tile[r][tx] = W[(size_t)(k0 + r) * N3 + n0 + tx];
    __syncthreads();
    #pragma unroll
    for (int r = ty; r < 32; r += 8)
        Wt[(size_t)(n0 + r) * KD + k0 + tx] = __float2bfloat16(tile[tx][r]);
}

// ---------------------------------------------------------------------------
// GEMM: G[m,n] = act( A[m,:] . Bt[n,:] + bias[n] ),  act = sigmoid for n>=H
// 256x256 tile, BK=64, 8 waves of 128x64, mfma_f32_16x16x32_bf16.
// 4 phases/K-tile, global_load_lds direct staging into just-consumed regions
// (prefetch distance 2 K-tiles), counted vmcnt(8) once per K-tile.
// CRITICAL (round 2): builtin s_barrier + CLOBBER-FREE waitcnt asm.
// "memory"-clobbered asm makes SIInsertWaitcnts conservatively drain
// vmcnt(0) lgkmcnt(0) before every asm -> kills the counted-vmcnt pipeline.
// Compiler-level ordering is restored with sched_barrier(0) only where the
// overwrite protocol needs it (after lgkmcnt(0) per rule #18; around the
// tile-boundary vmcnt wait so next-tile ds_reads can't hoist above it).
// ---------------------------------------------------------------------------
#define TILE_E (256 * 64)    // elements in one 256x64 bf16 LDS tile

__device__ __forceinline__ void gload16(const __hip_bfloat16* g, __hip_bfloat16* l)
{
    __builtin_amdgcn_global_load_lds(
        (const __attribute__((address_space(1))) void*)g,
        (__attribute__((address_space(3))) void*)l,
        16, 0, 0);
}

__global__ __launch_bounds__(512, 2)
void gemm_gates(const __hip_bfloat16* __restrict__ A,
                const __hip_bfloat16* __restrict__ Bt,
                const float* __restrict__ bias,
                __half* __restrict__ G)
{
    __shared__ __hip_bfloat16 sA[2 * TILE_E];   // 64 KiB
    __shared__ __hip_bfloat16 sB[2 * TILE_E];   // 64 KiB

    const int tid  = threadIdx.x;
    const int wave = tid >> 6;
    const int lane = tid & 63;
    const int l15  = lane & 15;
    const int quad = lane >> 4;

    // bijective XCD swizzle (nwg = 1536, 1536 % 8 == 0)
    int id = (int)blockIdx.x;
    id = (id & 7) * (1536 / 8) + (id >> 3);
    const int mt = id / (N3 / 256);
    const int nt = id % (N3 / 256);
    const int m0 = mt * 256;
    const int n0 = nt * 256;

    const int wm = (wave >> 2) * 128;   // 0 or 128
    const int wn = (wave & 3) * 64;     // 0,64,128,192

    // swizzled fragment column offsets (elements): col = kk*32 + quad*8
    const int swz = (l15 & 7) << 3;
    const int ce0 = (quad * 8) ^ swz;          // kk = 0
    const int ce1 = ce0 ^ 32;                  // kk = 1

    // staging geometry: each region = 64 rows x 64 cols = 512 thr x 16 B
    const int srr  = lane >> 3;                       // row within wave's strip
    const int sce  = ((lane & 7) * 8) ^ (srr << 3);   // pre-swizzled global col
    const int a_gr = m0 + wave * 8 + srr;             // + q*64
    const int b_gr = n0 + wave * 8 + srr;             // + q*64
    const int sloff = wave * 8 * 64;                  // wave-uniform LDS offset

    f32x4 acc[8][4] = {};

    // ---- prologue: stage K-tile 0 -> buf0, K-tile 1 -> buf1 ----
    #pragma unroll
    for (int q = 0; q < 4; ++q)
        gload16(A  + (size_t)(a_gr + q * 64) * KD + 0  + sce, sA + sloff + q * 4096);
    #pragma unroll
    for (int q = 0; q < 4; ++q)
        gload16(Bt + (size_t)(b_gr + q * 64) * KD + 0  + sce, sB + sloff + q * 4096);
    #pragma unroll
    for (int q = 0; q < 4; ++q)
        gload16(A  + (size_t)(a_gr + q * 64) * KD + 64 + sce, sA + TILE_E + sloff + q * 4096);
    #pragma unroll
    for (int q = 0; q < 4; ++q)
        gload16(Bt + (size_t)(b_gr + q * 64) * KD + 64 + sce, sB + TILE_E + sloff + q * 4096);

    asm volatile("s_waitcnt vmcnt(8)");
    __builtin_amdgcn_sched_barrier(0);
    __builtin_amdgcn_s_barrier();
    __builtin_amdgcn_sched_barrier(0);

    #pragma unroll 1
    for (int t = 0; t < 16; ++t) {
        __hip_bfloat16* pA = sA + (t & 1) * TILE_E;
        __hip_bfloat16* pB = sB + (t & 1) * TILE_E;
        const int ktn = t * 64 + 128;          // K-offset of K-tile t+2
        const bool st = (t < 14);

        bf16x8 af[4][2], b01[2][2], b23[2][2];

        // ================= phase 1: a(i0-3), b(t0-1) -> acc[0..3][0..1]
        #pragma unroll
        for (int i = 0; i < 4; ++i) {
            const int ro = (wm + i * 16 + l15) * 64;
            af[i][0] = *(const bf16x8*)(pA + ro + ce0);
            af[i][1] = *(const bf16x8*)(pA + ro + ce1);
        }
        #pragma unroll
        for (int j = 0; j < 2; ++j) {
            const int ro = (wn + j * 16 + l15) * 64;
            b01[j][0] = *(const bf16x8*)(pB + ro + ce0);
            b01[j][1] = *(const bf16x8*)(pB + ro + ce1);
        }
        __builtin_amdgcn_s_barrier();
        asm volatile("s_waitcnt lgkmcnt(0)");
        __builtin_amdgcn_sched_barrier(0);
        __builtin_amdgcn_s_setprio(1);
        #pragma unroll
        for (int i = 0; i < 4; ++i)
            #pragma unroll
            for (int j = 0; j < 2; ++j) {
                acc[i][j] = __builtin_amdgcn_mfma_f32_16x16x32_bf16(af[i][0], b01[j][0], acc[i][j], 0, 0, 0);
                acc[i][j] = __builtin_amdgcn_mfma_f32_16x16x32_bf16(af[i][1], b01[j][1], acc[i][j], 0, 0, 0);
            }
        __builtin_amdgcn_s_setprio(0);
        __builtin_amdgcn_s_barrier();

        // ================= phase 2: b(t2-3) -> acc[0..3][2..3]; stage A q0,q2
        #pragma unroll
        for (int j = 0; j < 2; ++j) {
            const int ro = (wn + (2 + j) * 16 + l15) * 64;
            b23[j][0] = *(const bf16x8*)(pB + ro + ce0);
            b23[j][1] = *(const bf16x8*)(pB + ro + ce1);
        }
        if (st) {  // A q0 (rows 0-63) and q2 (128-191): consumed in phase 1
            gload16(A + (size_t)(a_gr + 0 * 64) * KD + ktn + sce, pA + sloff + 0 * 4096);
            gload16(A + (size_t)(a_gr + 2 * 64) * KD + ktn + sce, pA + sloff + 2 * 4096);
        }
        __builtin_amdgcn_s_barrier();
        asm volatile("s_waitcnt lgkmcnt(0)");
        __builtin_amdgcn_sched_barrier(0);
        __builtin_amdgcn_s_setprio(1);
        #pragma unroll
        for (int i = 0; i < 4; ++i)
            #pragma unroll
            for (int j = 0; j < 2; ++j) {
                acc[i][2 + j] = __builtin_amdgcn_mfma_f32_16x16x32_bf16(af[i][0], b23[j][0], acc[i][2 + j], 0, 0, 0);
                acc[i][2 + j] = __builtin_amdgcn_mfma_f32_16x16x32_bf16(af[i][1], b23[j][1], acc[i][2 + j], 0, 0, 0);
            }
        __builtin_amdgcn_s_setprio(0);
        __builtin_amdgcn_s_barrier();

        // ================= phase 3: a(i4-7) -> acc[4..7][2..3]; stage B q0-q2
        #pragma unroll
        for (int i = 0; i < 4; ++i) {
            const int ro = (wm + 64 + i * 16 + l15) * 64;
            af[i][0] = *(const bf16x8*)(pA + ro + ce0);
            af[i][1] = *(const bf16x8*)(pA + ro + ce1);
        }
        if (st) {  // all of B consumed by end of phase 2
            gload16(Bt + (size_t)(b_gr + 0 * 64) * KD + ktn + sce, pB + sloff + 0 * 4096);
            gload16(Bt + (size_t)(b_gr + 1 * 64) * KD + ktn + sce, pB + sloff + 1 * 4096);
            gload16(Bt + (size_t)(b_gr + 2 * 64) * KD + ktn + sce, pB + sloff + 2 * 4096);
        }
        __builtin_amdgcn_s_barrier();
        asm volatile("s_waitcnt lgkmcnt(0)");
        __builtin_amdgcn_sched_barrier(0);
        __builtin_amdgcn_s_setprio(1);
        #pragma unroll
        for (int i = 0; i < 4; ++i)
            #pragma unroll
            for (int j = 0; j < 2; ++j) {
                acc[4 + i][2 + j] = __builtin_amdgcn_mfma_f32_16x16x32_bf16(af[i][0], b23[j][0], acc[4 + i][2 + j], 0, 0, 0);
                acc[4 + i][2 + j] = __builtin_amdgcn_mfma_f32_16x16x32_bf16(af[i][1], b23[j][1], acc[4 + i][2 + j], 0, 0, 0);
            }
        __builtin_amdgcn_s_setprio(0);
        __builtin_amdgcn_s_barrier();

        // ================= phase 4: regs only -> acc[4..7][0..1]; stage B q3, A q1,q3
        if (st) {  // B q3 consumed ph2; A q1 (64-127), q3 (192-255) consumed ph3
            gload16(Bt + (size_t)(b_gr + 3 * 64) * KD + ktn + sce, pB + sloff + 3 * 4096);
            gload16(A  + (size_t)(a_gr + 1 * 64) * KD + ktn + sce, pA + sloff + 1 * 4096);
            gload16(A  + (size_t)(a_gr + 3 * 64) * KD + ktn + sce, pA + sloff + 3 * 4096);
        }
        __builtin_amdgcn_s_barrier();
        __builtin_amdgcn_s_setprio(1);
        #pragma unroll
        for (int i = 0; i < 4; ++i)
            #pragma unroll
            for (int j = 0; j < 2; ++j) {
                acc[4 + i][j] = __builtin_amdgcn_mfma_f32_16x16x32_bf16(af[i][0], b01[j][0], acc[4 + i][j], 0, 0, 0);
                acc[4 + i][j] = __builtin_amdgcn_mfma_f32_16x16x32_bf16(af[i][1], b01[j][1], acc[4 + i][j], 0, 0, 0);
            }
        __builtin_amdgcn_s_setprio(0);
        // counted drain: leave this K-tile's 8 stage loads in flight,
        // guarantee K-tile t+1's loads have landed (then barrier joins waves)
        if (st) asm volatile("s_waitcnt vmcnt(8)");
        else    asm volatile("s_waitcnt vmcnt(0)");
        __builtin_amdgcn_sched_barrier(0);
        __builtin_amdgcn_s_barrier();
        __builtin_amdgcn_sched_barrier(0);
    }

    // ---- epilogue: bias + sigmoid(n>=H), fp16 store ----
    // D layout: row = quad*4 + r, col = l15
    #pragma unroll
    for (int tt = 0; tt < 4; ++tt) {
        const int n = n0 + wn + tt * 16 + l15;
        const float bv = bias[n];
        const bool sig = (n >= HD);
        #pragma unroll
        for (int i = 0; i < 8; ++i) {
            #pragma unroll
            for (int r = 0; r < 4; ++r) {
                const int m = m0 + wm + i * 16 + quad * 4 + r;
                float v = acc[i][tt][r] + bv;
                if (sig) v = sigmoid_f(v);
                G[(size_t)m * N3 + n] = __float2half(v);
            }
        }
    }
}

// ---------------------------------------------------------------------------
// Scan pass A: per-chunk affine composition. c_out = Aacc * c_in + Bacc
// ---------------------------------------------------------------------------
__global__ __launch_bounds__(256)
void scan_a(const __half* __restrict__ G,
            float* __restrict__ cA, float* __restrict__ cB)
{
    const int tid = threadIdx.x;
    const int h = (blockIdx.x & 3) * 256 + tid;
    const int b = (blockIdx.x >> 2) & 7;
    const int j = blockIdx.x >> 5;

    const size_t step = (size_t)BATCH * N3;
    const size_t base = ((size_t)(j * CHUNK) * BATCH + b) * N3;
    const __half* pu = G + base + h;
    const __half* pf = G + base + HD + h;

    float Aacc = 1.0f, Bacc = 0.0f;
    #pragma unroll 4
    for (int s = 0; s < CHUNK; ++s) {
        const float f = __half2float(*pf);
        const float u = __half2float(*pu);
        Bacc = f * Bacc + (1.0f - f) * u;
        Aacc *= f;
        pu += step; pf += step;
    }
    const int idx = (j * BATCH + b) * HD + h;
    cA[idx] = Aacc;
    cB[idx] = Bacc;
}

// ---------------------------------------------------------------------------
// Scan pass B: sequential prefix over chunks; emits chunk-start c and c_last
// ---------------------------------------------------------------------------
__global__ __launch_bounds__(256)
void scan_b(const float* __restrict__ cA, const float* __restrict__ cB,
            const float* __restrict__ h0,        // [B*H] slice for this layer
            float* __restrict__ cstart,          // [NCHUNK,B,H]
            float* __restrict__ c_out)           // [B*H] hidden slot (fp32)
{
    const int tid = blockIdx.x * 256 + threadIdx.x;  // 0..8191
    const int b = tid >> 10;
    const int h = tid & 1023;
    float c = h0[b * HD + h];
    #pragma unroll 8
    for (int j = 0; j < NCHUNK; ++j) {
        const int idx = (j * BATCH + b) * HD + h;
        cstart[idx] = c;
        c = cA[idx] * c + cB[idx];
    }
    c_out[b * HD + h] = c;
}

// ---------------------------------------------------------------------------
// Scan pass C: replay chunk; h = o*tanh(c) + (1-o)*x
// OUT_F32=false: write bf16 (layer-1 h1, may alias xin — read precedes write)
// OUT_F32=true : write fp32 (layer-2 final output)
// ---------------------------------------------------------------------------
template<bool OUT_F32>
__global__ __launch_bounds__(256)
void scan_c(const __half* __restrict__ G,
            const __hip_bfloat16* __restrict__ xin,
            const float* __restrict__ cstart,
            __hip_bfloat16* __restrict__ hout_bf,
            float* __restrict__ hout_f32)
{
    const int tid = threadIdx.x;
    const int h = (blockIdx.x & 3) * 256 + tid;
    const int b = (blockIdx.x >> 2) & 7;
    const int j = blockIdx.x >> 5;

    float c = cstart[(j * BATCH + b) * HD + h];

    const size_t mbase = (size_t)(j * CHUNK) * BATCH + b;
    const size_t stepg = (size_t)BATCH * N3;
    const size_t steph = (size_t)BATCH * HD;
    const __half* pu = G + mbase * N3 + h;
    const __half* pf = pu + HD;
    const __half* po = pu + 2 * HD;
    const __hip_bfloat16* px = xin + mbase * HD + h;
    __hip_bfloat16* pb = hout_bf ? hout_bf + mbase * HD + h : nullptr;
    float* pw = hout_f32 ? hout_f32 + mbase * HD + h : nullptr;

    #pragma unroll 4
    for (int s = 0; s < CHUNK; ++s) {
        const float f = __half2float(*pf);
        const float u = __half2float(*pu);
        const float o = __half2float(*po);
        const float x = __bfloat162float(*px);
        c = f * c + (1.0f - f) * u;
        const float hv = o * tanh_f(c) + (1.0f - o) * x;
        if (OUT_F32) { *pw = hv; pw += steph; }
        else         { *pb = __float2bfloat16(hv); pb += steph; }
        pu += stepg; pf += stepg; po += stepg; px += steph;
    }
}

// ---------------------------------------------------------------------------
extern "C" void kernel_launch(void* const* d_in, const int* in_sizes, int n_in,
                              void* d_out, int out_size, void* d_ws, size_t ws_size,
                              hipStream_t stream)
{
    const float* x  = (const float*)d_in[0];
    const float* h0 = (const float*)d_in[1];
    const float* W1 = (const float*)d_in[2];
    const float* b1 = (const float*)d_in[3];
    const float* W2 = (const float*)d_in[4];
    const float* b2 = (const float*)d_in[5];

    float* out     = (float*)d_out;
    float* h2_out  = out;                                  // [S,B,H] fp32
    float* hid_out = out + (size_t)S_LEN * BATCH * HD;     // [2,B,H] fp32

    // workspace carve-up (~268 MiB)
    char* ws = (char*)d_ws;
    auto carve = [&ws](size_t bytes) {
        char* p = ws;
        ws += (bytes + 255) & ~(size_t)255;
        return p;
    };
    const size_t G_BYTES   = (size_t)MTOT * N3 * 2;            // 192 MiB (fp16)
    const size_t XB_BYTES  = (size_t)MTOT * HD * 2;            // 64 MiB (bf16)
    const size_t WT_BYTES  = (size_t)N3 * KD * 2;              // 6 MiB (bf16)
    const size_t CAB_BYTES = (size_t)NCHUNK * BATCH * HD * 4;  // 2 MiB each

    __half* G           = (__half*)carve(G_BYTES);
    __hip_bfloat16* xb  = (__hip_bfloat16*)carve(XB_BYTES);  // x bf16; reused as h1
    __hip_bfloat16* Wt  = (__hip_bfloat16*)carve(WT_BYTES);
    float* cA           = (float*)carve(CAB_BYTES);
    float* cB           = (float*)carve(CAB_BYTES);
    float* cstart       = (float*)carve(CAB_BYTES);

    const dim3 tpb_t(32, 8);
    const dim3 grid_t(N3 / 32, KD / 32);
    const int  grid_gemm = (MTOT / 256) * (N3 / 256);   // 1536
    const int scan_blocks = NCHUNK * BATCH * 4;   // 2048
    const int cvt_blocks  = (int)(((size_t)MTOT * HD) / (256 * 8));  // 16384

    // ---- layer 1 ----
    cvt_f32_to_bf16<<<cvt_blocks, 256, 0, stream>>>(x, xb);
    transpose_w<<<grid_t, tpb_t, 0, stream>>>(W1, Wt);
    gemm_gates<<<grid_gemm, 512, 0, stream>>>(xb, Wt, b1, G);
    scan_a<<<scan_blocks, 256, 0, stream>>>(G, cA, cB);
    scan_b<<<32, 256, 0, stream>>>(cA, cB, h0, cstart, hid_out);
    // writes h1 over xb in place (per-element read precedes write)
    scan_c<false><<<scan_blocks, 256, 0, stream>>>(G, xb, cstart, xb, nullptr);

    // ---- layer 2 ----
    transpose_w<<<grid_t, tpb_t, 0, stream>>>(W2, Wt);
    gemm_gates<<<grid_gemm, 512, 0, stream>>>(xb, Wt, b2, G);
    scan_a<<<scan_blocks, 256, 0, stream>>>(G, cA, cB);
    scan_b<<<32, 256, 0, stream>>>(cA, cB, h0 + (size_t)BATCH * HD, cstart,
                                   hid_out + (size_t)BATCH * HD);
    scan_c<true><<<scan_blocks, 256, 0, stream>>>(G, xb, cstart, nullptr, h2_out);
}

// Round 3
// 943.706 us; speedup vs baseline: 1.0573x; 1.0403x over previous
//
#include <hip/hip_runtime.h>
#include <hip/hip_bf16.h>
#include <hip/hip_fp16.h>

// Problem dims (fixed)
#define S_LEN  4096
#define BATCH  8
#define HD     1024          // D == H
#define N3     3072          // 3H
#define MTOT   (S_LEN * BATCH)   // 32768 GEMM rows
#define KD     1024          // GEMM K
#define CHUNK  64
#define NCHUNK (S_LEN / CHUNK)   // 64

typedef __bf16 bf16x8 __attribute__((ext_vector_type(8)));
typedef float  f32x4  __attribute__((ext_vector_type(4)));

__device__ __forceinline__ float sigmoid_f(float x) {
    return 1.0f / (1.0f + __expf(-x));
}
__device__ __forceinline__ float tanh_f(float x) {
    return 1.0f - 2.0f / (__expf(2.0f * x) + 1.0f);
}

// ---------------------------------------------------------------------------
// fp32 -> bf16 elementwise convert (8 elems/thread, exact grid)
// ---------------------------------------------------------------------------
__global__ __launch_bounds__(256)
void cvt_f32_to_bf16(const float* __restrict__ in, __hip_bfloat16* __restrict__ out)
{
    const size_t i = ((size_t)blockIdx.x * 256 + threadIdx.x) * 8;
    const float4 a = *(const float4*)(in + i);
    const float4 b = *(const float4*)(in + i + 4);
    bf16x8 v;
    v[0] = (__bf16)a.x; v[1] = (__bf16)a.y; v[2] = (__bf16)a.z; v[3] = (__bf16)a.w;
    v[4] = (__bf16)b.x; v[5] = (__bf16)b.y; v[6] = (__bf16)b.z; v[7] = (__bf16)b.w;
    *(bf16x8*)((__bf16*)out + i) = v;
}

// ---------------------------------------------------------------------------
// W [K,N] fp32 -> Wt [N,K] bf16, 32x32 LDS tiles
// ---------------------------------------------------------------------------
__global__ __launch_bounds__(256)
void transpose_w(const float* __restrict__ W, __hip_bfloat16* __restrict__ Wt)
{
    __shared__ float tile[32][33];
    const int n0 = blockIdx.x * 32;
    const int k0 = blockIdx.y * 32;
    const int tx = threadIdx.x;      // 0..31
    const int ty = threadIdx.y;      // 0..7
    #pragma unroll
    for (int r = ty; r < 32; r += 8)
        tile[r][tx] = W[(size_t)(k0 + r) * N3 + n0 + tx];
    __syncthreads();
    #pragma unroll
    for (int r = ty; r < 32; r += 8)
        Wt[(size_t)(n0 + r) * KD + k0 + tx] = __float2bfloat16(tile[tx][r]);
}

// ---------------------------------------------------------------------------
// GEMM: G[m,n] = act( A[m,:] . Bt[n,:] + bias[n] ),  act = sigmoid for n>=H
// 256x256 tile, BK=64, 8 waves of 128x64, mfma_f32_16x16x32_bf16.
// Round 3: STRICT double buffer with STATIC (compile-time) buffer pointers.
// The backend inserts conservative vmcnt waits before ds_reads it cannot
// prove disjoint from outstanding LDS-DMA (global_load_lds) writes; the
// round-2 same-buffer region-prefetch (runtime t&1 base) defeated alias
// analysis and re-serialized every phase. Now: compute reads buf[cur],
// DMAs write buf[cur^1], both compile-time literals (loop processes 2
// tiles/iter) -> statically disjoint -> no inserted waits. Tile t+1's 8
// gloads issue in phases 1-2 of tile t (~2400 cyc head start), single
// vmcnt(0)+barrier at tile boundary. 4-phase ds_read/MFMA interleave,
// XOR swizzle (both-sides), setprio, bijective XCD swizzle unchanged.
// ---------------------------------------------------------------------------
#define TILE_E (256 * 64)    // elements in one 256x64 bf16 LDS tile

__device__ __forceinline__ void gload16(const __hip_bfloat16* g, __hip_bfloat16* l)
{
    __builtin_amdgcn_global_load_lds(
        (const __attribute__((address_space(1))) void*)g,
        (__attribute__((address_space(3))) void*)l,
        16, 0, 0);
}

__global__ __launch_bounds__(512, 2)
void gemm_gates(const __hip_bfloat16* __restrict__ A,
                const __hip_bfloat16* __restrict__ Bt,
                const float* __restrict__ bias,
                __half* __restrict__ G)
{
    __shared__ __hip_bfloat16 sA[2 * TILE_E];   // 64 KiB
    __shared__ __hip_bfloat16 sB[2 * TILE_E];   // 64 KiB

    const int tid  = threadIdx.x;
    const int wave = tid >> 6;
    const int lane = tid & 63;
    const int l15  = lane & 15;
    const int quad = lane >> 4;

    // bijective XCD swizzle (nwg = 1536, 1536 % 8 == 0)
    int id = (int)blockIdx.x;
    id = (id & 7) * (1536 / 8) + (id >> 3);
    const int mt = id / (N3 / 256);
    const int nt = id % (N3 / 256);
    const int m0 = mt * 256;
    const int n0 = nt * 256;

    const int wm = (wave >> 2) * 128;   // 0 or 128
    const int wn = (wave & 3) * 64;     // 0,64,128,192

    // swizzled fragment column offsets (elements): col = kk*32 + quad*8
    const int swz = (l15 & 7) << 3;
    const int ce0 = (quad * 8) ^ swz;          // kk = 0
    const int ce1 = ce0 ^ 32;                  // kk = 1

    // staging geometry: each region = 64 rows x 64 cols = 512 thr x 16 B
    const int srr  = lane >> 3;                       // row within wave's strip
    const int sce  = ((lane & 7) * 8) ^ (srr << 3);   // pre-swizzled global col
    const int a_gr = m0 + wave * 8 + srr;             // + q*64
    const int b_gr = n0 + wave * 8 + srr;             // + q*64
    const int sloff = wave * 8 * 64;                  // wave-uniform LDS offset

    f32x4 acc[8][4] = {};

    // ---- prologue: stage K-tile 0 -> buf0, drain, join ----
    #pragma unroll
    for (int q = 0; q < 4; ++q)
        gload16(A  + (size_t)(a_gr + q * 64) * KD + 0 + sce, sA + sloff + q * 4096);
    #pragma unroll
    for (int q = 0; q < 4; ++q)
        gload16(Bt + (size_t)(b_gr + q * 64) * KD + 0 + sce, sB + sloff + q * 4096);

    asm volatile("s_waitcnt vmcnt(0)");
    __builtin_amdgcn_sched_barrier(0);
    __builtin_amdgcn_s_barrier();
    __builtin_amdgcn_sched_barrier(0);

    // tile body: compute from (cA_,cB_); stage tile t+1 into (nA_,nB_)
    auto tile = [&](const int t,
                    const __hip_bfloat16* cA_, const __hip_bfloat16* cB_,
                    __hip_bfloat16* nA_, __hip_bfloat16* nB_) {
        const int ktn = (t + 1) * 64;
        const bool st = (t < 15);

        bf16x8 af[4][2], b01[2][2], b23[2][2];

        // ===== phase 1: read a(i0-3), b(j0-1); stage A(t+1); acc[0..3][0..1]
        #pragma unroll
        for (int i = 0; i < 4; ++i) {
            const int ro = (wm + i * 16 + l15) * 64;
            af[i][0] = *(const bf16x8*)(cA_ + ro + ce0);
            af[i][1] = *(const bf16x8*)(cA_ + ro + ce1);
        }
        #pragma unroll
        for (int j = 0; j < 2; ++j) {
            const int ro = (wn + j * 16 + l15) * 64;
            b01[j][0] = *(const bf16x8*)(cB_ + ro + ce0);
            b01[j][1] = *(const bf16x8*)(cB_ + ro + ce1);
        }
        if (st) {
            #pragma unroll
            for (int q = 0; q < 4; ++q)
                gload16(A + (size_t)(a_gr + q * 64) * KD + ktn + sce,
                        nA_ + sloff + q * 4096);
        }
        __builtin_amdgcn_s_barrier();
        asm volatile("s_waitcnt lgkmcnt(0)");
        __builtin_amdgcn_sched_barrier(0);
        __builtin_amdgcn_s_setprio(1);
        #pragma unroll
        for (int i = 0; i < 4; ++i)
            #pragma unroll
            for (int j = 0; j < 2; ++j) {
                acc[i][j] = __builtin_amdgcn_mfma_f32_16x16x32_bf16(af[i][0], b01[j][0], acc[i][j], 0, 0, 0);
                acc[i][j] = __builtin_amdgcn_mfma_f32_16x16x32_bf16(af[i][1], b01[j][1], acc[i][j], 0, 0, 0);
            }
        __builtin_amdgcn_s_setprio(0);
        __builtin_amdgcn_s_barrier();

        // ===== phase 2: read b(j2-3); stage B(t+1); acc[0..3][2..3]
        #pragma unroll
        for (int j = 0; j < 2; ++j) {
            const int ro = (wn + (2 + j) * 16 + l15) * 64;
            b23[j][0] = *(const bf16x8*)(cB_ + ro + ce0);
            b23[j][1] = *(const bf16x8*)(cB_ + ro + ce1);
        }
        if (st) {
            #pragma unroll
            for (int q = 0; q < 4; ++q)
                gload16(Bt + (size_t)(b_gr + q * 64) * KD + ktn + sce,
                        nB_ + sloff + q * 4096);
        }
        __builtin_amdgcn_s_barrier();
        asm volatile("s_waitcnt lgkmcnt(0)");
        __builtin_amdgcn_sched_barrier(0);
        __builtin_amdgcn_s_setprio(1);
        #pragma unroll
        for (int i = 0; i < 4; ++i)
            #pragma unroll
            for (int j = 0; j < 2; ++j) {
                acc[i][2 + j] = __builtin_amdgcn_mfma_f32_16x16x32_bf16(af[i][0], b23[j][0], acc[i][2 + j], 0, 0, 0);
                acc[i][2 + j] = __builtin_amdgcn_mfma_f32_16x16x32_bf16(af[i][1], b23[j][1], acc[i][2 + j], 0, 0, 0);
            }
        __builtin_amdgcn_s_setprio(0);
        __builtin_amdgcn_s_barrier();

        // ===== phase 3: read a(i4-7); acc[4..7][2..3]
        #pragma unroll
        for (int i = 0; i < 4; ++i) {
            const int ro = (wm + 64 + i * 16 + l15) * 64;
            af[i][0] = *(const bf16x8*)(cA_ + ro + ce0);
            af[i][1] = *(const bf16x8*)(cA_ + ro + ce1);
        }
        __builtin_amdgcn_s_barrier();
        asm volatile("s_waitcnt lgkmcnt(0)");
        __builtin_amdgcn_sched_barrier(0);
        __builtin_amdgcn_s_setprio(1);
        #pragma unroll
        for (int i = 0; i < 4; ++i)
            #pragma unroll
            for (int j = 0; j < 2; ++j) {
                acc[4 + i][2 + j] = __builtin_amdgcn_mfma_f32_16x16x32_bf16(af[i][0], b23[j][0], acc[4 + i][2 + j], 0, 0, 0);
                acc[4 + i][2 + j] = __builtin_amdgcn_mfma_f32_16x16x32_bf16(af[i][1], b23[j][1], acc[4 + i][2 + j], 0, 0, 0);
            }
        __builtin_amdgcn_s_setprio(0);
        __builtin_amdgcn_s_barrier();

        // ===== phase 4: regs only; acc[4..7][0..1]; boundary drain + join
        __builtin_amdgcn_s_setprio(1);
        #pragma unroll
        for (int i = 0; i < 4; ++i)
            #pragma unroll
            for (int j = 0; j < 2; ++j) {
                acc[4 + i][j] = __builtin_amdgcn_mfma_f32_16x16x32_bf16(af[i][0], b01[j][0], acc[4 + i][j], 0, 0, 0);
                acc[4 + i][j] = __builtin_amdgcn_mfma_f32_16x16x32_bf16(af[i][1], b01[j][1], acc[4 + i][j], 0, 0, 0);
            }
        __builtin_amdgcn_s_setprio(0);
        asm volatile("s_waitcnt vmcnt(0)");
        __builtin_amdgcn_sched_barrier(0);
        __builtin_amdgcn_s_barrier();
        __builtin_amdgcn_sched_barrier(0);
    };

    #pragma unroll 1
    for (int th = 0; th < 8; ++th) {
        tile(2 * th,     sA,          sB,          sA + TILE_E, sB + TILE_E);
        tile(2 * th + 1, sA + TILE_E, sB + TILE_E, sA,          sB);
    }

    // ---- epilogue: bias + sigmoid(n>=H), fp16 store ----
    // D layout: row = quad*4 + r, col = l15
    #pragma unroll
    for (int tt = 0; tt < 4; ++tt) {
        const int n = n0 + wn + tt * 16 + l15;
        const float bv = bias[n];
        const bool sig = (n >= HD);
        #pragma unroll
        for (int i = 0; i < 8; ++i) {
            #pragma unroll
            for (int r = 0; r < 4; ++r) {
                const int m = m0 + wm + i * 16 + quad * 4 + r;
                float v = acc[i][tt][r] + bv;
                if (sig) v = sigmoid_f(v);
                G[(size_t)m * N3 + n] = __float2half(v);
            }
        }
    }
}

// ---------------------------------------------------------------------------
// Scan pass A: per-chunk affine composition. c_out = Aacc * c_in + Bacc
// ---------------------------------------------------------------------------
__global__ __launch_bounds__(256)
void scan_a(const __half* __restrict__ G,
            float* __restrict__ cA, float* __restrict__ cB)
{
    const int tid = threadIdx.x;
    const int h = (blockIdx.x & 3) * 256 + tid;
    const int b = (blockIdx.x >> 2) & 7;
    const int j = blockIdx.x >> 5;

    const size_t step = (size_t)BATCH * N3;
    const size_t base = ((size_t)(j * CHUNK) * BATCH + b) * N3;
    const __half* pu = G + base + h;
    const __half* pf = G + base + HD + h;

    float Aacc = 1.0f, Bacc = 0.0f;
    #pragma unroll 4
    for (int s = 0; s < CHUNK; ++s) {
        const float f = __half2float(*pf);
        const float u = __half2float(*pu);
        Bacc = f * Bacc + (1.0f - f) * u;
        Aacc *= f;
        pu += step; pf += step;
    }
    const int idx = (j * BATCH + b) * HD + h;
    cA[idx] = Aacc;
    cB[idx] = Bacc;
}

// ---------------------------------------------------------------------------
// Scan pass B: sequential prefix over chunks; emits chunk-start c and c_last
// ---------------------------------------------------------------------------
__global__ __launch_bounds__(256)
void scan_b(const float* __restrict__ cA, const float* __restrict__ cB,
            const float* __restrict__ h0,        // [B*H] slice for this layer
            float* __restrict__ cstart,          // [NCHUNK,B,H]
            float* __restrict__ c_out)           // [B*H] hidden slot (fp32)
{
    const int tid = blockIdx.x * 256 + threadIdx.x;  // 0..8191
    const int b = tid >> 10;
    const int h = tid & 1023;
    float c = h0[b * HD + h];
    #pragma unroll 8
    for (int j = 0; j < NCHUNK; ++j) {
        const int idx = (j * BATCH + b) * HD + h;
        cstart[idx] = c;
        c = cA[idx] * c + cB[idx];
    }
    c_out[b * HD + h] = c;
}

// ---------------------------------------------------------------------------
// Scan pass C: replay chunk; h = o*tanh(c) + (1-o)*x
// OUT_F32=false: write bf16 (layer-1 h1, may alias xin — read precedes write)
// OUT_F32=true : write fp32 (layer-2 final output)
// ---------------------------------------------------------------------------
template<bool OUT_F32>
__global__ __launch_bounds__(256)
void scan_c(const __half* __restrict__ G,
            const __hip_bfloat16* __restrict__ xin,
            const float* __restrict__ cstart,
            __hip_bfloat16* __restrict__ hout_bf,
            float* __restrict__ hout_f32)
{
    const int tid = threadIdx.x;
    const int h = (blockIdx.x & 3) * 256 + tid;
    const int b = (blockIdx.x >> 2) & 7;
    const int j = blockIdx.x >> 5;

    float c = cstart[(j * BATCH + b) * HD + h];

    const size_t mbase = (size_t)(j * CHUNK) * BATCH + b;
    const size_t stepg = (size_t)BATCH * N3;
    const size_t steph = (size_t)BATCH * HD;
    const __half* pu = G + mbase * N3 + h;
    const __half* pf = pu + HD;
    const __half* po = pu + 2 * HD;
    const __hip_bfloat16* px = xin + mbase * HD + h;
    __hip_bfloat16* pb = hout_bf ? hout_bf + mbase * HD + h : nullptr;
    float* pw = hout_f32 ? hout_f32 + mbase * HD + h : nullptr;

    #pragma unroll 4
    for (int s = 0; s < CHUNK; ++s) {
        const float f = __half2float(*pf);
        const float u = __half2float(*pu);
        const float o = __half2float(*po);
        const float x = __bfloat162float(*px);
        c = f * c + (1.0f - f) * u;
        const float hv = o * tanh_f(c) + (1.0f - o) * x;
        if (OUT_F32) { *pw = hv; pw += steph; }
        else         { *pb = __float2bfloat16(hv); pb += steph; }
        pu += stepg; pf += stepg; po += stepg; px += steph;
    }
}

// ---------------------------------------------------------------------------
extern "C" void kernel_launch(void* const* d_in, const int* in_sizes, int n_in,
                              void* d_out, int out_size, void* d_ws, size_t ws_size,
                              hipStream_t stream)
{
    const float* x  = (const float*)d_in[0];
    const float* h0 = (const float*)d_in[1];
    const float* W1 = (const float*)d_in[2];
    const float* b1 = (const float*)d_in[3];
    const float* W2 = (const float*)d_in[4];
    const float* b2 = (const float*)d_in[5];

    float* out     = (float*)d_out;
    float* h2_out  = out;                                  // [S,B,H] fp32
    float* hid_out = out + (size_t)S_LEN * BATCH * HD;     // [2,B,H] fp32

    // workspace carve-up (~268 MiB)
    char* ws = (char*)d_ws;
    auto carve = [&ws](size_t bytes) {
        char* p = ws;
        ws += (bytes + 255) & ~(size_t)255;
        return p;
    };
    const size_t G_BYTES   = (size_t)MTOT * N3 * 2;            // 192 MiB (fp16)
    const size_t XB_BYTES  = (size_t)MTOT * HD * 2;            // 64 MiB (bf16)
    const size_t WT_BYTES  = (size_t)N3 * KD * 2;              // 6 MiB (bf16)
    const size_t CAB_BYTES = (size_t)NCHUNK * BATCH * HD * 4;  // 2 MiB each

    __half* G           = (__half*)carve(G_BYTES);
    __hip_bfloat16* xb  = (__hip_bfloat16*)carve(XB_BYTES);  // x bf16; reused as h1
    __hip_bfloat16* Wt  = (__hip_bfloat16*)carve(WT_BYTES);
    float* cA           = (float*)carve(CAB_BYTES);
    float* cB           = (float*)carve(CAB_BYTES);
    float* cstart       = (float*)carve(CAB_BYTES);

    const dim3 tpb_t(32, 8);
    const dim3 grid_t(N3 / 32, KD / 32);
    const int  grid_gemm = (MTOT / 256) * (N3 / 256);   // 1536
    const int scan_blocks = NCHUNK * BATCH * 4;   // 2048
    const int cvt_blocks  = (int)(((size_t)MTOT * HD) / (256 * 8));  // 16384

    // ---- layer 1 ----
    cvt_f32_to_bf16<<<cvt_blocks, 256, 0, stream>>>(x, xb);
    transpose_w<<<grid_t, tpb_t, 0, stream>>>(W1, Wt);
    gemm_gates<<<grid_gemm, 512, 0, stream>>>(xb, Wt, b1, G);
    scan_a<<<scan_blocks, 256, 0, stream>>>(G, cA, cB);
    scan_b<<<32, 256, 0, stream>>>(cA, cB, h0, cstart, hid_out);
    // writes h1 over xb in place (per-element read precedes write)
    scan_c<false><<<scan_blocks, 256, 0, stream>>>(G, xb, cstart, xb, nullptr);

    // ---- layer 2 ----
    transpose_w<<<grid_t, tpb_t, 0, stream>>>(W2, Wt);
    gemm_gates<<<grid_gemm, 512, 0, stream>>>(xb, Wt, b2, G);
    scan_a<<<scan_blocks, 256, 0, stream>>>(G, cA, cB);
    scan_b<<<32, 256, 0, stream>>>(cA, cB, h0 + (size_t)BATCH * HD, cstart,
                                   hid_out + (size_t)BATCH * HD);
    scan_c<true><<<scan_blocks, 256, 0, stream>>>(G, xb, cstart, nullptr, h2_out);
}

// Round 4
// 942.278 us; speedup vs baseline: 1.0589x; 1.0015x over previous
//
#include <hip/hip_runtime.h>
#include <hip/hip_bf16.h>
#include <hip/hip_fp16.h>

// Problem dims (fixed)
#define S_LEN  4096
#define BATCH  8
#define HD     1024          // D == H
#define N3     3072          // 3H
#define MTOT   (S_LEN * BATCH)   // 32768 GEMM rows
#define KD     1024          // GEMM K
#define CHUNK  64
#define NCHUNK (S_LEN / CHUNK)   // 64

typedef __bf16 bf16x8 __attribute__((ext_vector_type(8)));
typedef float  f32x4  __attribute__((ext_vector_type(4)));

__device__ __forceinline__ float sigmoid_f(float x) {
    return 1.0f / (1.0f + __expf(-x));
}
__device__ __forceinline__ float tanh_f(float x) {
    return 1.0f - 2.0f / (__expf(2.0f * x) + 1.0f);
}

// ---------------------------------------------------------------------------
// fp32 -> bf16 elementwise convert (8 elems/thread, exact grid)
// ---------------------------------------------------------------------------
__global__ __launch_bounds__(256)
void cvt_f32_to_bf16(const float* __restrict__ in, __hip_bfloat16* __restrict__ out)
{
    const size_t i = ((size_t)blockIdx.x * 256 + threadIdx.x) * 8;
    const float4 a = *(const float4*)(in + i);
    const float4 b = *(const float4*)(in + i + 4);
    bf16x8 v;
    v[0] = (__bf16)a.x; v[1] = (__bf16)a.y; v[2] = (__bf16)a.z; v[3] = (__bf16)a.w;
    v[4] = (__bf16)b.x; v[5] = (__bf16)b.y; v[6] = (__bf16)b.z; v[7] = (__bf16)b.w;
    *(bf16x8*)((__bf16*)out + i) = v;
}

// ---------------------------------------------------------------------------
// W [K,N] fp32 -> Wt [N,K] bf16, 32x32 LDS tiles
// ---------------------------------------------------------------------------
__global__ __launch_bounds__(256)
void transpose_w(const float* __restrict__ W, __hip_bfloat16* __restrict__ Wt)
{
    __shared__ float tile[32][33];
    const int n0 = blockIdx.x * 32;
    const int k0 = blockIdx.y * 32;
    const int tx = threadIdx.x;      // 0..31
    const int ty = threadIdx.y;      // 0..7
    #pragma unroll
    for (int r = ty; r < 32; r += 8)
        tile[r][tx] = W[(size_t)(k0 + r) * N3 + n0 + tx];
    __syncthreads();
    #pragma unroll
    for (int r = ty; r < 32; r += 8)
        Wt[(size_t)(n0 + r) * KD + k0 + tx] = __float2bfloat16(tile[tx][r]);
}

// ---------------------------------------------------------------------------
// GEMM: G[m,n] = act( A[m,:] . Bt[n,:] + bias[n] ),  act = sigmoid for n>=H
// 256x256 tile, BK=64, 8 waves of 128x64, mfma_f32_16x16x32_bf16.
// Round 4: FRAGMENT-PIPELINED tile, ONE barrier per K-tile.
// Rounds 1-3 all serialized the per-phase LDS burst against the MFMA
// cluster (barrier -> lgkmcnt(0) drain -> MFMA), adding ~2300 cyc of LDS
// service time to 2480 cyc of MFMA per tile instead of overlapping them
// (MfmaUtil pinned ~26%). Now: 4 batches of 16 MFMA; ds_reads for batch
// s+1 issued BEFORE batch s's MFMAs with counted lgkmcnt(N); no mid-tile
// barriers (race-free: each wave retires reads via lgkmcnt before the
// boundary barrier and drains its own DMAs via vmcnt(0) pre-barrier).
// Static double buffer, distance-1 prefetch via global_load_lds.
// XOR swizzle (both-sides), setprio around MFMA, XCD swizzle unchanged.
// ---------------------------------------------------------------------------
#define TILE_E (256 * 64)    // elements in one 256x64 bf16 LDS tile

__device__ __forceinline__ void gload16(const __hip_bfloat16* g, __hip_bfloat16* l)
{
    __builtin_amdgcn_global_load_lds(
        (const __attribute__((address_space(1))) void*)g,
        (__attribute__((address_space(3))) void*)l,
        16, 0, 0);
}

__global__ __launch_bounds__(512, 2)
void gemm_gates(const __hip_bfloat16* __restrict__ A,
                const __hip_bfloat16* __restrict__ Bt,
                const float* __restrict__ bias,
                __half* __restrict__ G)
{
    __shared__ __hip_bfloat16 sA[2 * TILE_E];   // 64 KiB
    __shared__ __hip_bfloat16 sB[2 * TILE_E];   // 64 KiB

    const int tid  = threadIdx.x;
    const int wave = tid >> 6;
    const int lane = tid & 63;
    const int l15  = lane & 15;
    const int quad = lane >> 4;

    // bijective XCD swizzle (nwg = 1536, 1536 % 8 == 0)
    int id = (int)blockIdx.x;
    id = (id & 7) * (1536 / 8) + (id >> 3);
    const int mt = id / (N3 / 256);
    const int nt = id % (N3 / 256);
    const int m0 = mt * 256;
    const int n0 = nt * 256;

    const int wm = (wave >> 2) * 128;   // 0 or 128
    const int wn = (wave & 3) * 64;     // 0,64,128,192

    // swizzled fragment column offsets (elements): col = kk*32 + quad*8
    const int swz = (l15 & 7) << 3;
    const int ce0 = (quad * 8) ^ swz;          // kk = 0
    const int ce1 = ce0 ^ 32;                  // kk = 1

    // staging geometry: each region = 64 rows x 64 cols = 512 thr x 16 B
    const int srr  = lane >> 3;                       // row within wave's strip
    const int sce  = ((lane & 7) * 8) ^ (srr << 3);   // pre-swizzled global col
    const int a_gr = m0 + wave * 8 + srr;             // + q*64
    const int b_gr = n0 + wave * 8 + srr;             // + q*64
    const int sloff = wave * 8 * 64;                  // wave-uniform LDS offset

    f32x4 acc[8][4] = {};

    // ---- prologue: stage K-tile 0 -> buf0, drain, join ----
    #pragma unroll
    for (int q = 0; q < 4; ++q)
        gload16(A  + (size_t)(a_gr + q * 64) * KD + 0 + sce, sA + sloff + q * 4096);
    #pragma unroll
    for (int q = 0; q < 4; ++q)
        gload16(Bt + (size_t)(b_gr + q * 64) * KD + 0 + sce, sB + sloff + q * 4096);

    asm volatile("s_waitcnt vmcnt(0)");
    __builtin_amdgcn_sched_barrier(0);
    __builtin_amdgcn_s_barrier();
    __builtin_amdgcn_sched_barrier(0);

    // tile body: compute from (cA_,cB_); stage tile t+1 into (nA_,nB_)
    auto tile = [&](const int t,
                    const __hip_bfloat16* cA_, const __hip_bfloat16* cB_,
                    __hip_bfloat16* nA_, __hip_bfloat16* nB_) {
        const int ktn = (t + 1) * 64;
        const bool st = (t < 15);

        bf16x8 aLo0[4], aHi0[4], aLo1[4], aHi1[4], bk0[4], bk1[4];

        // R1: A m0-3 kk0 (4) + B n0-3 kk0 (4)            [8 reads]
        #pragma unroll
        for (int i = 0; i < 4; ++i)
            aLo0[i] = *(const bf16x8*)(cA_ + (wm + i * 16 + l15) * 64 + ce0);
        #pragma unroll
        for (int j = 0; j < 4; ++j)
            bk0[j]  = *(const bf16x8*)(cB_ + (wn + j * 16 + l15) * 64 + ce0);
        __builtin_amdgcn_sched_barrier(0);
        // G-loads: A -> next buffer
        if (st) {
            #pragma unroll
            for (int q = 0; q < 4; ++q)
                gload16(A + (size_t)(a_gr + q * 64) * KD + ktn + sce,
                        nA_ + sloff + q * 4096);
        }
        __builtin_amdgcn_sched_barrier(0);
        // R2: A m4-7 kk0 (4) + B n0-3 kk1 (4)            [8 reads]
        #pragma unroll
        for (int i = 0; i < 4; ++i)
            aHi0[i] = *(const bf16x8*)(cA_ + (wm + 64 + i * 16 + l15) * 64 + ce0);
        #pragma unroll
        for (int j = 0; j < 4; ++j)
            bk1[j]  = *(const bf16x8*)(cB_ + (wn + j * 16 + l15) * 64 + ce1);
        __builtin_amdgcn_sched_barrier(0);
        asm volatile("s_waitcnt lgkmcnt(8)");   // R1 landed, R2 in flight
        __builtin_amdgcn_sched_barrier(0);
        // S1: (m0-3 x n0-3, kk0) -> 16 MFMA
        __builtin_amdgcn_s_setprio(1);
        #pragma unroll
        for (int i = 0; i < 4; ++i)
            #pragma unroll
            for (int j = 0; j < 4; ++j)
                acc[i][j] = __builtin_amdgcn_mfma_f32_16x16x32_bf16(aLo0[i], bk0[j], acc[i][j], 0, 0, 0);
        __builtin_amdgcn_s_setprio(0);
        __builtin_amdgcn_sched_barrier(0);
        // G-loads: B -> next buffer
        if (st) {
            #pragma unroll
            for (int q = 0; q < 4; ++q)
                gload16(Bt + (size_t)(b_gr + q * 64) * KD + ktn + sce,
                        nB_ + sloff + q * 4096);
        }
        // R3: A m0-3 kk1 (4)
        #pragma unroll
        for (int i = 0; i < 4; ++i)
            aLo1[i] = *(const bf16x8*)(cA_ + (wm + i * 16 + l15) * 64 + ce1);
        __builtin_amdgcn_sched_barrier(0);
        asm volatile("s_waitcnt lgkmcnt(4)");   // R2 landed, R3 in flight
        __builtin_amdgcn_sched_barrier(0);
        // S2: (m4-7 x n0-3, kk0)
        __builtin_amdgcn_s_setprio(1);
        #pragma unroll
        for (int i = 0; i < 4; ++i)
            #pragma unroll
            for (int j = 0; j < 4; ++j)
                acc[4 + i][j] = __builtin_amdgcn_mfma_f32_16x16x32_bf16(aHi0[i], bk0[j], acc[4 + i][j], 0, 0, 0);
        __builtin_amdgcn_s_setprio(0);
        __builtin_amdgcn_sched_barrier(0);
        // R4: A m4-7 kk1 (4)
        #pragma unroll
        for (int i = 0; i < 4; ++i)
            aHi1[i] = *(const bf16x8*)(cA_ + (wm + 64 + i * 16 + l15) * 64 + ce1);
        __builtin_amdgcn_sched_barrier(0);
        asm volatile("s_waitcnt lgkmcnt(4)");   // R3 landed, R4 in flight
        __builtin_amdgcn_sched_barrier(0);
        // S3: (m0-3 x n0-3, kk1)
        __builtin_amdgcn_s_setprio(1);
        #pragma unroll
        for (int i = 0; i < 4; ++i)
            #pragma unroll
            for (int j = 0; j < 4; ++j)
                acc[i][j] = __builtin_amdgcn_mfma_f32_16x16x32_bf16(aLo1[i], bk1[j], acc[i][j], 0, 0, 0);
        __builtin_amdgcn_s_setprio(0);
        __builtin_amdgcn_sched_barrier(0);
        asm volatile("s_waitcnt lgkmcnt(0)");   // R4 landed
        __builtin_amdgcn_sched_barrier(0);
        // S4: (m4-7 x n0-3, kk1)
        __builtin_amdgcn_s_setprio(1);
        #pragma unroll
        for (int i = 0; i < 4; ++i)
            #pragma unroll
            for (int j = 0; j < 4; ++j)
                acc[4 + i][j] = __builtin_amdgcn_mfma_f32_16x16x32_bf16(aHi1[i], bk1[j], acc[4 + i][j], 0, 0, 0);
        __builtin_amdgcn_s_setprio(0);
        __builtin_amdgcn_sched_barrier(0);
        // boundary: own DMAs drained (issued ~3 batches ago), then join
        asm volatile("s_waitcnt vmcnt(0)");
        __builtin_amdgcn_sched_barrier(0);
        __builtin_amdgcn_s_barrier();
        __builtin_amdgcn_sched_barrier(0);
    };

    #pragma unroll 1
    for (int th = 0; th < 8; ++th) {
        tile(2 * th,     sA,          sB,          sA + TILE_E, sB + TILE_E);
        tile(2 * th + 1, sA + TILE_E, sB + TILE_E, sA,          sB);
    }

    // ---- epilogue: bias + sigmoid(n>=H), fp16 store ----
    // D layout: row = quad*4 + r, col = l15
    #pragma unroll
    for (int tt = 0; tt < 4; ++tt) {
        const int n = n0 + wn + tt * 16 + l15;
        const float bv = bias[n];
        const bool sig = (n >= HD);
        #pragma unroll
        for (int i = 0; i < 8; ++i) {
            #pragma unroll
            for (int r = 0; r < 4; ++r) {
                const int m = m0 + wm + i * 16 + quad * 4 + r;
                float v = acc[i][tt][r] + bv;
                if (sig) v = sigmoid_f(v);
                G[(size_t)m * N3 + n] = __float2half(v);
            }
        }
    }
}

// ---------------------------------------------------------------------------
// Scan pass A: per-chunk affine composition. c_out = Aacc * c_in + Bacc
// ---------------------------------------------------------------------------
__global__ __launch_bounds__(256)
void scan_a(const __half* __restrict__ G,
            float* __restrict__ cA, float* __restrict__ cB)
{
    const int tid = threadIdx.x;
    const int h = (blockIdx.x & 3) * 256 + tid;
    const int b = (blockIdx.x >> 2) & 7;
    const int j = blockIdx.x >> 5;

    const size_t step = (size_t)BATCH * N3;
    const size_t base = ((size_t)(j * CHUNK) * BATCH + b) * N3;
    const __half* pu = G + base + h;
    const __half* pf = G + base + HD + h;

    float Aacc = 1.0f, Bacc = 0.0f;
    #pragma unroll 4
    for (int s = 0; s < CHUNK; ++s) {
        const float f = __half2float(*pf);
        const float u = __half2float(*pu);
        Bacc = f * Bacc + (1.0f - f) * u;
        Aacc *= f;
        pu += step; pf += step;
    }
    const int idx = (j * BATCH + b) * HD + h;
    cA[idx] = Aacc;
    cB[idx] = Bacc;
}

// ---------------------------------------------------------------------------
// Scan pass B: sequential prefix over chunks; emits chunk-start c and c_last
// ---------------------------------------------------------------------------
__global__ __launch_bounds__(256)
void scan_b(const float* __restrict__ cA, const float* __restrict__ cB,
            const float* __restrict__ h0,        // [B*H] slice for this layer
            float* __restrict__ cstart,          // [NCHUNK,B,H]
            float* __restrict__ c_out)           // [B*H] hidden slot (fp32)
{
    const int tid = blockIdx.x * 256 + threadIdx.x;  // 0..8191
    const int b = tid >> 10;
    const int h = tid & 1023;
    float c = h0[b * HD + h];
    #pragma unroll 8
    for (int j = 0; j < NCHUNK; ++j) {
        const int idx = (j * BATCH + b) * HD + h;
        cstart[idx] = c;
        c = cA[idx] * c + cB[idx];
    }
    c_out[b * HD + h] = c;
}

// ---------------------------------------------------------------------------
// Scan pass C: replay chunk; h = o*tanh(c) + (1-o)*x
// OUT_F32=false: write bf16 (layer-1 h1, may alias xin — read precedes write)
// OUT_F32=true : write fp32 (layer-2 final output)
// ---------------------------------------------------------------------------
template<bool OUT_F32>
__global__ __launch_bounds__(256)
void scan_c(const __half* __restrict__ G,
            const __hip_bfloat16* __restrict__ xin,
            const float* __restrict__ cstart,
            __hip_bfloat16* __restrict__ hout_bf,
            float* __restrict__ hout_f32)
{
    const int tid = threadIdx.x;
    const int h = (blockIdx.x & 3) * 256 + tid;
    const int b = (blockIdx.x >> 2) & 7;
    const int j = blockIdx.x >> 5;

    float c = cstart[(j * BATCH + b) * HD + h];

    const size_t mbase = (size_t)(j * CHUNK) * BATCH + b;
    const size_t stepg = (size_t)BATCH * N3;
    const size_t steph = (size_t)BATCH * HD;
    const __half* pu = G + mbase * N3 + h;
    const __half* pf = pu + HD;
    const __half* po = pu + 2 * HD;
    const __hip_bfloat16* px = xin + mbase * HD + h;
    __hip_bfloat16* pb = hout_bf ? hout_bf + mbase * HD + h : nullptr;
    float* pw = hout_f32 ? hout_f32 + mbase * HD + h : nullptr;

    #pragma unroll 4
    for (int s = 0; s < CHUNK; ++s) {
        const float f = __half2float(*pf);
        const float u = __half2float(*pu);
        const float o = __half2float(*po);
        const float x = __bfloat162float(*px);
        c = f * c + (1.0f - f) * u;
        const float hv = o * tanh_f(c) + (1.0f - o) * x;
        if (OUT_F32) { *pw = hv; pw += steph; }
        else         { *pb = __float2bfloat16(hv); pb += steph; }
        pu += stepg; pf += stepg; po += stepg; px += steph;
    }
}

// ---------------------------------------------------------------------------
extern "C" void kernel_launch(void* const* d_in, const int* in_sizes, int n_in,
                              void* d_out, int out_size, void* d_ws, size_t ws_size,
                              hipStream_t stream)
{
    const float* x  = (const float*)d_in[0];
    const float* h0 = (const float*)d_in[1];
    const float* W1 = (const float*)d_in[2];
    const float* b1 = (const float*)d_in[3];
    const float* W2 = (const float*)d_in[4];
    const float* b2 = (const float*)d_in[5];

    float* out     = (float*)d_out;
    float* h2_out  = out;                                  // [S,B,H] fp32
    float* hid_out = out + (size_t)S_LEN * BATCH * HD;     // [2,B,H] fp32

    // workspace carve-up (~268 MiB)
    char* ws = (char*)d_ws;
    auto carve = [&ws](size_t bytes) {
        char* p = ws;
        ws += (bytes + 255) & ~(size_t)255;
        return p;
    };
    const size_t G_BYTES   = (size_t)MTOT * N3 * 2;            // 192 MiB (fp16)
    const size_t XB_BYTES  = (size_t)MTOT * HD * 2;            // 64 MiB (bf16)
    const size_t WT_BYTES  = (size_t)N3 * KD * 2;              // 6 MiB (bf16)
    const size_t CAB_BYTES = (size_t)NCHUNK * BATCH * HD * 4;  // 2 MiB each

    __half* G           = (__half*)carve(G_BYTES);
    __hip_bfloat16* xb  = (__hip_bfloat16*)carve(XB_BYTES);  // x bf16; reused as h1
    __hip_bfloat16* Wt  = (__hip_bfloat16*)carve(WT_BYTES);
    float* cA           = (float*)carve(CAB_BYTES);
    float* cB           = (float*)carve(CAB_BYTES);
    float* cstart       = (float*)carve(CAB_BYTES);

    const dim3 tpb_t(32, 8);
    const dim3 grid_t(N3 / 32, KD / 32);
    const int  grid_gemm = (MTOT / 256) * (N3 / 256);   // 1536
    const int scan_blocks = NCHUNK * BATCH * 4;   // 2048
    const int cvt_blocks  = (int)(((size_t)MTOT * HD) / (256 * 8));  // 16384

    // ---- layer 1 ----
    cvt_f32_to_bf16<<<cvt_blocks, 256, 0, stream>>>(x, xb);
    transpose_w<<<grid_t, tpb_t, 0, stream>>>(W1, Wt);
    gemm_gates<<<grid_gemm, 512, 0, stream>>>(xb, Wt, b1, G);
    scan_a<<<scan_blocks, 256, 0, stream>>>(G, cA, cB);
    scan_b<<<32, 256, 0, stream>>>(cA, cB, h0, cstart, hid_out);
    // writes h1 over xb in place (per-element read precedes write)
    scan_c<false><<<scan_blocks, 256, 0, stream>>>(G, xb, cstart, xb, nullptr);

    // ---- layer 2 ----
    transpose_w<<<grid_t, tpb_t, 0, stream>>>(W2, Wt);
    gemm_gates<<<grid_gemm, 512, 0, stream>>>(xb, Wt, b2, G);
    scan_a<<<scan_blocks, 256, 0, stream>>>(G, cA, cB);
    scan_b<<<32, 256, 0, stream>>>(cA, cB, h0 + (size_t)BATCH * HD, cstart,
                                   hid_out + (size_t)BATCH * HD);
    scan_c<true><<<scan_blocks, 256, 0, stream>>>(G, xb, cstart, nullptr, h2_out);
}